// Round 8
// baseline (1754.899 us; speedup 1.0000x reference)
//
#include <hip/hip_runtime.h>
#include <hip/hip_bf16.h>

typedef __attribute__((ext_vector_type(8))) short  bf16x8;
typedef __attribute__((ext_vector_type(4))) float  f32x4;
typedef __attribute__((ext_vector_type(8))) unsigned short u16x8;
typedef __attribute__((ext_vector_type(4))) unsigned short u16x4;

__device__ __forceinline__ unsigned short f2b(float f) {
    unsigned int u = __builtin_bit_cast(unsigned int, f);
    u += 0x7FFFu + ((u >> 16) & 1u);
    return (unsigned short)(u >> 16);
}
__device__ __forceinline__ float b2f(unsigned short u) {
    return __builtin_bit_cast(float, (unsigned int)u << 16);
}
// tanh-form GELU: max abs err vs exact ~1e-3, well under the 0.109 threshold
__device__ __forceinline__ float gelu_fast(float x) {
    float u = 0.7978845608f * x * (1.0f + 0.044715f * x * x);
    float au = fabsf(u);
    float e = __expf(-2.0f * au);
    float t = (1.0f - e) / (1.0f + e);
    t = copysignf(t, u);
    return 0.5f * x * (1.0f + t);
}
// windowed row m -> original row (b*65536 + y*256 + x)
__device__ __forceinline__ int wperm(int m) {
    int w = m >> 6, n = m & 63;
    int b = w >> 10, wy = (w >> 5) & 31, wx = w & 31;
    int y = wy * 8 + (n >> 3), xx = wx * 8 + (n & 7);
    return (b << 16) + (y << 8) + xx;
}
// original row r -> windowed row m
__device__ __forceinline__ int wperm_inv(int r) {
    int rb = r >> 16, ry = (r >> 8) & 255, rx = r & 255;
    return (((rb << 10) + ((ry >> 3) << 5) + (rx >> 3)) << 6) + ((ry & 7) << 3) + (rx & 7);
}

// ---------------- prep kernels ----------------
__global__ void transpose_w(const float* __restrict__ in, unsigned short* __restrict__ out,
                            int K, int N) {
    int i = blockIdx.x * 256 + threadIdx.x;
    if (i >= K * N) return;
    int n = i / K, k = i - n * K;
    out[i] = f2b(in[k * N + n]);
}

__global__ __launch_bounds__(256) void cpb_kernel(
    const float* __restrict__ scale, const float* __restrict__ w1, const float* __restrict__ b1,
    const float* __restrict__ w2, const float* __restrict__ b2, float* __restrict__ btab) {
    int t = threadIdx.x;
    if (t >= 225) return;
    int i = t / 15, j = t - (t / 15) * 15;
    float ti = (i - 7) * (8.0f / 7.0f);
    float tj = (j - 7) * (8.0f / 7.0f);
    float s0 = scale[0], s1 = scale[1];
    float acc[6];
    #pragma unroll
    for (int h = 0; h < 6; ++h) acc[h] = b2[h];
    for (int k = 0; k < 512; ++k) {
        float hv = ti * w1[k] + tj * w1[512 + k] + s0 * w1[1024 + k] + s1 * w1[1536 + k] + b1[k];
        hv = fmaxf(hv, 0.f);
        #pragma unroll
        for (int h = 0; h < 6; ++h) acc[h] += hv * w2[k * 6 + h];
    }
    #pragma unroll
    for (int h = 0; h < 6; ++h) btab[t * 6 + h] = acc[h];
}

__global__ __launch_bounds__(256) void ln_stats(const float* __restrict__ x, float* __restrict__ st) {
    int r = blockIdx.x * 4 + (threadIdx.x >> 6);
    int lane = threadIdx.x & 63;
    const float* p = x + (size_t)r * 192;
    float a0 = p[lane], a1 = p[lane + 64], a2 = p[lane + 128];
    float s = a0 + a1 + a2;
    float q = a0 * a0 + a1 * a1 + a2 * a2;
    #pragma unroll
    for (int off = 1; off < 64; off <<= 1) {
        s += __shfl_xor(s, off);
        q += __shfl_xor(q, off);
    }
    if (lane == 0) {
        float m = s * (1.f / 192.f);
        float v = q * (1.f / 192.f) - m * m;
        st[2 * r] = m;
        st[2 * r + 1] = rsqrtf(v + 1e-5f);
    }
}

// LN (stats + apply) in one pass; writes bf16 rows in WINDOWED order.
__global__ __launch_bounds__(256) void ln_full(
    const float* __restrict__ xin, const float* __restrict__ g, const float* __restrict__ b,
    unsigned short* __restrict__ ow) {
    int r = blockIdx.x * 4 + (threadIdx.x >> 6);
    int lane = threadIdx.x & 63;
    const float* p = xin + (size_t)r * 192;
    float a0 = p[lane], a1 = p[lane + 64], a2 = p[lane + 128];
    float s = a0 + a1 + a2;
    float q = a0 * a0 + a1 * a1 + a2 * a2;
    #pragma unroll
    for (int off = 1; off < 64; off <<= 1) {
        s += __shfl_xor(s, off);
        q += __shfl_xor(q, off);
    }
    float mean = s * (1.f / 192.f);
    float rstd = rsqrtf(q * (1.f / 192.f) - mean * mean + 1e-5f);
    unsigned short* o = ow + (size_t)wperm_inv(r) * 192;
    o[lane]       = f2b((a0 - mean) * rstd * g[lane] + b[lane]);
    o[lane + 64]  = f2b((a1 - mean) * rstd * g[lane + 64] + b[lane + 64]);
    o[lane + 128] = f2b((a2 - mean) * rstd * g[lane + 128] + b[lane + 128]);
}

// ---------------- shared GEMM (K=192), tile 128x192, 4 waves ----------------
// MODE 0: A = xnw bf16 (windowed LN1(x)) -> q/k/v scatter (q scaled)
// MODE 1: A = attn_out bf16 (windowed) -> d_out[perm] = x[perm] + A@W + b
// MODE 2: A = LN2(d_out) computed from fp32+stats -> m1 = gelu(A@W+b) bf16
// MODE 3: A = on2w bf16 (windowed LN2) -> m1[wperm] = gelu(A@W+b) bf16
template<int MODE>
__global__ __launch_bounds__(256) void gemm192(
    const float* __restrict__ Af, const unsigned short* __restrict__ Ab,
    const float* __restrict__ stats, const float* __restrict__ lng, const float* __restrict__ lnb,
    const unsigned short* __restrict__ Bt, const float* __restrict__ bias,
    unsigned short* __restrict__ oq, unsigned short* __restrict__ ok2, unsigned short* __restrict__ ov,
    const float* __restrict__ resid, float* __restrict__ ofp, unsigned short* __restrict__ obf) {
    __shared__ __align__(16) unsigned short As[128 * 72];
    __shared__ __align__(16) unsigned short Bs[192 * 72];
    const int t = threadIdx.x;
    const int lane = t & 63;
    const int wv = t >> 6, wm = wv >> 1, wn = wv & 1;
    const int n0 = blockIdx.x * 192;
    const int m0 = blockIdx.y * 128;
    const int l15 = lane & 15, lq = lane >> 4;

    f32x4 acc[4][6];
    #pragma unroll
    for (int i = 0; i < 4; ++i)
        #pragma unroll
        for (int j = 0; j < 6; ++j) acc[i][j] = (f32x4){0.f, 0.f, 0.f, 0.f};

    for (int k0 = 0; k0 < 192; k0 += 64) {
        if constexpr (MODE == 2) {
            #pragma unroll
            for (int i = 0; i < 8; ++i) {
                int c = t + i * 256;
                int row = c >> 4, ch = c & 15;
                int m = m0 + row;
                f32x4 v = *(const f32x4*)(Af + (size_t)m * 192 + k0 + ch * 4);
                float mean = stats[2 * m], rstd = stats[2 * m + 1];
                u16x4 pk;
                #pragma unroll
                for (int j = 0; j < 4; ++j) {
                    int kk = k0 + ch * 4 + j;
                    pk[j] = f2b((v[j] - mean) * rstd * lng[kk] + lnb[kk]);
                }
                *(u16x4*)&As[row * 72 + ch * 4] = pk;
            }
        } else {
            #pragma unroll
            for (int i = 0; i < 4; ++i) {
                int c = t + i * 256;
                int row = c >> 3, ch = c & 7;
                *(u16x8*)&As[row * 72 + ch * 8] =
                    *(const u16x8*)(Ab + (size_t)(m0 + row) * 192 + k0 + ch * 8);
            }
        }
        #pragma unroll
        for (int i = 0; i < 6; ++i) {
            int c = t + i * 256;
            int row = c >> 3, ch = c & 7;
            *(u16x8*)&Bs[row * 72 + ch * 8] =
                *(const u16x8*)(Bt + (size_t)(n0 + row) * 192 + k0 + ch * 8);
        }
        __syncthreads();
        #pragma unroll
        for (int kk = 0; kk < 2; ++kk) {
            bf16x8 a[4], bb[6];
            #pragma unroll
            for (int mt = 0; mt < 4; ++mt)
                a[mt] = *(bf16x8*)&As[(wm * 64 + mt * 16 + l15) * 72 + kk * 32 + lq * 8];
            #pragma unroll
            for (int nt = 0; nt < 6; ++nt)
                bb[nt] = *(bf16x8*)&Bs[(wn * 96 + nt * 16 + l15) * 72 + kk * 32 + lq * 8];
            #pragma unroll
            for (int mt = 0; mt < 4; ++mt)
                #pragma unroll
                for (int nt = 0; nt < 6; ++nt)
                    acc[mt][nt] = __builtin_amdgcn_mfma_f32_16x16x32_bf16(a[mt], bb[nt], acc[mt][nt], 0, 0, 0);
        }
        __syncthreads();
    }
    #pragma unroll
    for (int mt = 0; mt < 4; ++mt) {
        #pragma unroll
        for (int nt = 0; nt < 6; ++nt) {
            #pragma unroll
            for (int r = 0; r < 4; ++r) {
                int m = m0 + wm * 64 + mt * 16 + lq * 4 + r;
                int c = n0 + wn * 96 + nt * 16 + l15;
                float v = acc[mt][nt][r] + bias[c];
                if constexpr (MODE == 0) {
                    int which = c / 192;
                    int head = (c % 192) >> 5;
                    int d = c & 31;
                    int w = m >> 6, n = m & 63;
                    unsigned short* dst = (which == 0) ? oq : (which == 1) ? ok2 : ov;
                    if (which == 0) v *= 0.17677669529663689f;  // HD^-0.5
                    dst[((size_t)(w * 6 + head) * 64 + n) * 32 + d] = f2b(v);
                } else if constexpr (MODE == 1) {
                    int r2 = wperm(m);
                    size_t idx = (size_t)r2 * 192 + c;
                    ofp[idx] = resid[idx] + v;
                } else if constexpr (MODE == 2) {
                    obf[(size_t)m * 768 + c] = f2b(gelu_fast(v));
                } else {
                    obf[(size_t)wperm(m) * 768 + c] = f2b(gelu_fast(v));
                }
            }
        }
    }
}

// ---------------- attention: one wave per (window, head) ----------------
__global__ __launch_bounds__(64) void attn_win(
    const unsigned short* __restrict__ qb, const unsigned short* __restrict__ kb,
    const unsigned short* __restrict__ vb, const float* __restrict__ btab,
    unsigned short* __restrict__ ao) {
    __shared__ float sb[1350];
    __shared__ __align__(16) unsigned short pl[64 * 72];
    __shared__ __align__(16) unsigned short vT[32 * 72];
    const int bid = blockIdx.x;            // = w*6 + h
    const int w = bid / 6, h = bid - w * 6;
    const int lane = threadIdx.x;
    const int l15 = lane & 15, lq = lane >> 4;

    for (int i = lane; i < 1350; i += 64) sb[i] = btab[i];

    const unsigned short* qp = qb + (size_t)bid * 2048;
    const unsigned short* kp = kb + (size_t)bid * 2048;
    const unsigned short* vp = vb + (size_t)bid * 2048;

    bf16x8 qf[4], kf[4];
    #pragma unroll
    for (int i = 0; i < 4; ++i) {
        qf[i] = *(const bf16x8*)(qp + (i * 16 + l15) * 32 + lq * 8);
        kf[i] = *(const bf16x8*)(kp + (i * 16 + l15) * 32 + lq * 8);
    }
    #pragma unroll
    for (int i = 0; i < 4; ++i) {  // V transposed into LDS
        int c = lane + i * 64;
        int mr = c >> 2, d0 = (c & 3) * 8;
        u16x8 v = *(const u16x8*)(vp + mr * 32 + d0);
        #pragma unroll
        for (int j = 0; j < 8; ++j) vT[(d0 + j) * 72 + mr] = v[j];
    }
    f32x4 s[4][4];
    #pragma unroll
    for (int mt = 0; mt < 4; ++mt)
        #pragma unroll
        for (int nt = 0; nt < 4; ++nt)
            s[mt][nt] = __builtin_amdgcn_mfma_f32_16x16x32_bf16(
                qf[mt], kf[nt], (f32x4){0.f, 0.f, 0.f, 0.f}, 0, 0, 0);
    __syncthreads();
    // bias + softmax (rows over 16 lanes x 4 col-tiles)
    #pragma unroll
    for (int mt = 0; mt < 4; ++mt) {
        #pragma unroll
        for (int r = 0; r < 4; ++r) {
            int n = mt * 16 + lq * 4 + r;
            int ny = n >> 3, nx = n & 7;
            float sv[4];
            float mx = -1e30f;
            #pragma unroll
            for (int nt = 0; nt < 4; ++nt) {
                int m = nt * 16 + l15;
                int idx = (ny - (m >> 3) + 7) * 15 + (nx - (m & 7) + 7);
                float val = s[mt][nt][r] + sb[idx * 6 + h];
                sv[nt] = val;
                mx = fmaxf(mx, val);
            }
            #pragma unroll
            for (int off = 1; off < 16; off <<= 1) mx = fmaxf(mx, __shfl_xor(mx, off));
            float sum = 0.f;
            #pragma unroll
            for (int nt = 0; nt < 4; ++nt) { sv[nt] = __expf(sv[nt] - mx); sum += sv[nt]; }
            #pragma unroll
            for (int off = 1; off < 16; off <<= 1) sum += __shfl_xor(sum, off);
            float inv = 1.f / sum;
            #pragma unroll
            for (int nt = 0; nt < 4; ++nt)
                pl[n * 72 + nt * 16 + l15] = f2b(sv[nt] * inv);
        }
    }
    __syncthreads();
    f32x4 o[4][2];
    #pragma unroll
    for (int i = 0; i < 4; ++i)
        #pragma unroll
        for (int j = 0; j < 2; ++j) o[i][j] = (f32x4){0.f, 0.f, 0.f, 0.f};
    #pragma unroll
    for (int mt = 0; mt < 4; ++mt)
        #pragma unroll
        for (int kk = 0; kk < 2; ++kk) {
            bf16x8 a = *(bf16x8*)&pl[(mt * 16 + l15) * 72 + kk * 32 + lq * 8];
            #pragma unroll
            for (int dt = 0; dt < 2; ++dt) {
                bf16x8 b = *(bf16x8*)&vT[(dt * 16 + l15) * 72 + kk * 32 + lq * 8];
                o[mt][dt] = __builtin_amdgcn_mfma_f32_16x16x32_bf16(a, b, o[mt][dt], 0, 0, 0);
            }
        }
    #pragma unroll
    for (int mt = 0; mt < 4; ++mt)
        #pragma unroll
        for (int dt = 0; dt < 2; ++dt)
            #pragma unroll
            for (int r = 0; r < 4; ++r) {
                int n = mt * 16 + lq * 4 + r;
                int d = dt * 16 + l15;
                ao[((size_t)w * 64 + n) * 192 + h * 32 + d] = f2b(o[mt][dt][r]);
            }
}

// -------- fused depthwise 3x3 conv + gelu + fc2 + residual ------------------
// v7: 4-wave blocks, tile 64px = 32x * 2y, launch_bounds(256,3):
//   reg cap 512/3 = 170 total; kernel needs ~84 arch + 48 agpr = 132 -> NO
//   spill (v4/v6 spilled at the 128 cap of min_waves=4), and 3 waves/SIMD ->
//   3 independent blocks/CU (LDS 36.9KB*3=111KB ok) -> cross-block latency
//   hiding that v5's 8-wave block (1 block/CU) lacked.
// Conv: per kx hold 3 tap-weight vectors; stream 4 source rows into both
// output rows on the fly (12 input + 9 weight loads/thread/chunk, no row buf).
__global__ __launch_bounds__(256, 3) void conv_fc2_v7(
    const unsigned short* __restrict__ m1, const unsigned short* __restrict__ dwwT,
    const float* __restrict__ dwb, const unsigned short* __restrict__ fc2T,
    const float* __restrict__ fc2b, float* __restrict__ out) {
    __shared__ __align__(16) unsigned short As[64 * 72];
    __shared__ __align__(16) unsigned short Bs[192 * 72];
    const int t = threadIdx.x;
    // XCD band swizzle: each XCD gets a contiguous 64-row band
    const int g = ((blockIdx.x & 7) << 8) + (blockIdx.x >> 3);
    const int b = g >> 10, ypair = (g >> 3) & 127, xq = g & 7;
    const int y0 = ypair * 2, x0 = xq * 32;
    const int cg = t & 7, lx = t >> 3;               // lx in [0,32)
    const size_t ibase = (size_t)b * 65536;

    const int lane = t & 63, wv = t >> 6, wm = wv >> 1, wn = wv & 1;
    const int l15 = lane & 15, lq = lane >> 4;

    f32x4 acc[2][6];
    #pragma unroll
    for (int i = 0; i < 2; ++i)
        #pragma unroll
        for (int j = 0; j < 6; ++j) acc[i][j] = (f32x4){0.f, 0.f, 0.f, 0.f};

    for (int k0 = 0; k0 < 768; k0 += 64) {
        const int c0 = k0 + cg * 8;
        // ---- conv: 1 col x, 2 output rows, 8 ch per thread ----
        float a[2][8];
        f32x4 bs0 = *(const f32x4*)(dwb + c0);
        f32x4 bs1 = *(const f32x4*)(dwb + c0 + 4);
        #pragma unroll
        for (int i = 0; i < 2; ++i) {
            #pragma unroll
            for (int j = 0; j < 4; ++j) { a[i][j] = bs0[j]; a[i][4 + j] = bs1[j]; }
        }
        #pragma unroll
        for (int kx = -1; kx <= 1; ++kx) {
            int xx = x0 + lx + kx;
            bool xv = (unsigned)xx < 256u;
            float wv3[3][8];
            #pragma unroll
            for (int ky = 0; ky < 3; ++ky) {
                u16x8 w8 = *(const u16x8*)(dwwT + (ky * 3 + kx + 1) * 768 + c0);
                #pragma unroll
                for (int j = 0; j < 8; ++j) wv3[ky][j] = b2f(w8[j]);
            }
            #pragma unroll
            for (int ry = 0; ry < 4; ++ry) {       // source row y0-1+ry
                int yy = y0 - 1 + ry;
                float in8[8];
                if (xv && (unsigned)yy < 256u) {
                    u16x8 in = *(const u16x8*)(m1 + ((ibase + (size_t)yy * 256 + xx) * 768 + c0));
                    #pragma unroll
                    for (int j = 0; j < 8; ++j) in8[j] = b2f(in[j]);
                } else {
                    #pragma unroll
                    for (int j = 0; j < 8; ++j) in8[j] = 0.f;
                }
                if (ry < 3) {
                    #pragma unroll
                    for (int j = 0; j < 8; ++j) a[0][j] += in8[j] * wv3[ry][j];
                }
                if (ry >= 1) {
                    #pragma unroll
                    for (int j = 0; j < 8; ++j) a[1][j] += in8[j] * wv3[ry - 1][j];
                }
            }
        }
        #pragma unroll
        for (int i = 0; i < 2; ++i) {
            u16x8 o;
            #pragma unroll
            for (int j = 0; j < 8; ++j) o[j] = f2b(gelu_fast(a[i][j]));
            *(u16x8*)&As[(i * 32 + lx) * 72 + cg * 8] = o;
        }
        // ---- B staging: fc2T[192][k0..k0+64) ----
        #pragma unroll
        for (int i = 0; i < 6; ++i) {
            int c = t + i * 256;
            int nr = c >> 3, ch = c & 7;
            *(u16x8*)&Bs[nr * 72 + ch * 8] =
                *(const u16x8*)(fc2T + (size_t)nr * 768 + k0 + ch * 8);
        }
        __syncthreads();
        #pragma unroll
        for (int kk = 0; kk < 2; ++kk) {
            bf16x8 af[2], bb[6];
            #pragma unroll
            for (int mt = 0; mt < 2; ++mt)
                af[mt] = *(bf16x8*)&As[(wm * 32 + mt * 16 + l15) * 72 + kk * 32 + lq * 8];
            #pragma unroll
            for (int nt = 0; nt < 6; ++nt)
                bb[nt] = *(bf16x8*)&Bs[(wn * 96 + nt * 16 + l15) * 72 + kk * 32 + lq * 8];
            #pragma unroll
            for (int mt = 0; mt < 2; ++mt)
                #pragma unroll
                for (int nt = 0; nt < 6; ++nt)
                    acc[mt][nt] = __builtin_amdgcn_mfma_f32_16x16x32_bf16(af[mt], bb[nt], acc[mt][nt], 0, 0, 0);
        }
        __syncthreads();
    }
    #pragma unroll
    for (int mt = 0; mt < 2; ++mt)
        #pragma unroll
        for (int nt = 0; nt < 6; ++nt)
            #pragma unroll
            for (int r = 0; r < 4; ++r) {
                int ml = wm * 32 + mt * 16 + lq * 4 + r;
                int iy = ml >> 5, lxx = ml & 31;
                int col = wn * 96 + nt * 16 + l15;
                size_t idx = (ibase + (size_t)(y0 + iy) * 256 + x0 + lxx) * 192 + col;
                out[idx] = out[idx] + acc[mt][nt][r] + fc2b[col];
            }
}

// ---------------- host ----------------
extern "C" void kernel_launch(void* const* d_in, const int* in_sizes, int n_in,
                              void* d_out, int out_size, void* d_ws, size_t ws_size,
                              hipStream_t stream) {
    (void)in_sizes; (void)n_in; (void)out_size;
    const float* x     = (const float*)d_in[0];
    const float* scale = (const float*)d_in[1];
    const float* n1g   = (const float*)d_in[2];
    const float* n1b   = (const float*)d_in[3];
    const float* qkvw  = (const float*)d_in[4];
    const float* qkvb  = (const float*)d_in[5];
    const float* projw = (const float*)d_in[6];
    const float* projb = (const float*)d_in[7];
    const float* cw1   = (const float*)d_in[8];
    const float* cb1   = (const float*)d_in[9];
    const float* cw2   = (const float*)d_in[10];
    const float* cb2   = (const float*)d_in[11];
    const float* n2g   = (const float*)d_in[12];
    const float* n2b   = (const float*)d_in[13];
    const float* fc1w  = (const float*)d_in[14];
    const float* fc1b  = (const float*)d_in[15];
    const float* fc2w  = (const float*)d_in[16];
    const float* fc2b  = (const float*)d_in[17];
    const float* dww   = (const float*)d_in[18];
    const float* dwb   = (const float*)d_in[19];
    float* out = (float*)d_out;

    char* ws = (char*)d_ws;
    unsigned short* qkvT  = (unsigned short*)ws;       // [576][192]
    unsigned short* projT = qkvT + 110592;             // [192][192]
    unsigned short* fc1T  = projT + 36864;             // [768][192]
    unsigned short* fc2T  = fc1T + 147456;             // [192][768]
    unsigned short* dwwT  = fc2T + 147456;             // [9][768] tap-major bf16
    float* btab  = (float*)(ws + 1048576);             // [225][6]
    float* stats = (float*)(ws + 2097152);             // [131072][2]
    unsigned short* pool = (unsigned short*)(ws + 4194304);
    const size_t S = 25165824;                          // 50.3MB slots (ushort count)
    unsigned short* qb = pool;
    unsigned short* kb = pool + S;
    unsigned short* vb = pool + 2 * S;
    unsigned short* ab = pool + 3 * S;
    unsigned short* m1 = pool;                          // [2*65536][768] bf16 (201.3MB)
    unsigned short* on2w = pool + 4 * S;                // optional 5th slot
    unsigned short* xnw = (unsigned short*)d_out;       // LN1 bf16 (windowed), d_out as scratch
    const bool five_slots = ws_size >= (size_t)4194304 + (size_t)5 * S * 2;

    transpose_w<<<432, 256, 0, stream>>>(qkvw, qkvT, 192, 576);
    transpose_w<<<144, 256, 0, stream>>>(projw, projT, 192, 192);
    transpose_w<<<576, 256, 0, stream>>>(fc1w, fc1T, 192, 768);
    transpose_w<<<576, 256, 0, stream>>>(fc2w, fc2T, 768, 192);
    transpose_w<<<27, 256, 0, stream>>>(dww, dwwT, 768, 9);   // dwwT[tap*768+c]=dww[c*9+tap]
    cpb_kernel<<<1, 256, 0, stream>>>(scale, cw1, cb1, cw2, cb2, btab);

    ln_full<<<32768, 256, 0, stream>>>(x, n1g, n1b, xnw);
    gemm192<0><<<dim3(3, 1024), 256, 0, stream>>>(
        (const float*)nullptr, xnw, (const float*)nullptr, (const float*)nullptr,
        (const float*)nullptr, qkvT, qkvb,
        qb, kb, vb, (const float*)nullptr, (float*)nullptr, (unsigned short*)nullptr);
    attn_win<<<12288, 64, 0, stream>>>(qb, kb, vb, btab, ab);
    gemm192<1><<<dim3(1, 1024), 256, 0, stream>>>(
        (const float*)nullptr, ab, (const float*)nullptr, (const float*)nullptr,
        (const float*)nullptr, projT, projb,
        (unsigned short*)nullptr, (unsigned short*)nullptr, (unsigned short*)nullptr,
        x, out, (unsigned short*)nullptr);
    if (five_slots) {
        ln_full<<<32768, 256, 0, stream>>>(out, n2g, n2b, on2w);
        gemm192<3><<<dim3(4, 1024), 256, 0, stream>>>(
            (const float*)nullptr, on2w, (const float*)nullptr, (const float*)nullptr,
            (const float*)nullptr, fc1T, fc1b,
            (unsigned short*)nullptr, (unsigned short*)nullptr, (unsigned short*)nullptr,
            (const float*)nullptr, (float*)nullptr, m1);
    } else {
        ln_stats<<<32768, 256, 0, stream>>>(out, stats);
        gemm192<2><<<dim3(4, 1024), 256, 0, stream>>>(
            out, (const unsigned short*)nullptr, stats, n2g, n2b, fc1T, fc1b,
            (unsigned short*)nullptr, (unsigned short*)nullptr, (unsigned short*)nullptr,
            (const float*)nullptr, (float*)nullptr, m1);
    }
    conv_fc2_v7<<<2048, 256, 0, stream>>>(m1, dwwT, dwb, fc2T, fc2b, out);
}

// Round 9
// 860.410 us; speedup vs baseline: 2.0396x; 2.0396x over previous
//
#include <hip/hip_runtime.h>
#include <hip/hip_bf16.h>

typedef __attribute__((ext_vector_type(8))) short  bf16x8;
typedef __attribute__((ext_vector_type(4))) float  f32x4;
typedef __attribute__((ext_vector_type(8))) unsigned short u16x8;
typedef __attribute__((ext_vector_type(4))) unsigned short u16x4;

__device__ __forceinline__ unsigned short f2b(float f) {
    unsigned int u = __builtin_bit_cast(unsigned int, f);
    u += 0x7FFFu + ((u >> 16) & 1u);
    return (unsigned short)(u >> 16);
}
__device__ __forceinline__ float b2f(unsigned short u) {
    return __builtin_bit_cast(float, (unsigned int)u << 16);
}
// tanh-form GELU: max abs err vs exact ~1e-3, well under the 0.109 threshold
__device__ __forceinline__ float gelu_fast(float x) {
    float u = 0.7978845608f * x * (1.0f + 0.044715f * x * x);
    float au = fabsf(u);
    float e = __expf(-2.0f * au);
    float t = (1.0f - e) / (1.0f + e);
    t = copysignf(t, u);
    return 0.5f * x * (1.0f + t);
}
// windowed row m -> original row (b*65536 + y*256 + x)
__device__ __forceinline__ int wperm(int m) {
    int w = m >> 6, n = m & 63;
    int b = w >> 10, wy = (w >> 5) & 31, wx = w & 31;
    int y = wy * 8 + (n >> 3), xx = wx * 8 + (n & 7);
    return (b << 16) + (y << 8) + xx;
}
// original row r -> windowed row m
__device__ __forceinline__ int wperm_inv(int r) {
    int rb = r >> 16, ry = (r >> 8) & 255, rx = r & 255;
    return (((rb << 10) + ((ry >> 3) << 5) + (rx >> 3)) << 6) + ((ry & 7) << 3) + (rx & 7);
}

// ---------------- prep kernels ----------------
__global__ void transpose_w(const float* __restrict__ in, unsigned short* __restrict__ out,
                            int K, int N) {
    int i = blockIdx.x * 256 + threadIdx.x;
    if (i >= K * N) return;
    int n = i / K, k = i - n * K;
    out[i] = f2b(in[k * N + n]);
}

__global__ __launch_bounds__(256) void cpb_kernel(
    const float* __restrict__ scale, const float* __restrict__ w1, const float* __restrict__ b1,
    const float* __restrict__ w2, const float* __restrict__ b2, float* __restrict__ btab) {
    int t = threadIdx.x;
    if (t >= 225) return;
    int i = t / 15, j = t - (t / 15) * 15;
    float ti = (i - 7) * (8.0f / 7.0f);
    float tj = (j - 7) * (8.0f / 7.0f);
    float s0 = scale[0], s1 = scale[1];
    float acc[6];
    #pragma unroll
    for (int h = 0; h < 6; ++h) acc[h] = b2[h];
    for (int k = 0; k < 512; ++k) {
        float hv = ti * w1[k] + tj * w1[512 + k] + s0 * w1[1024 + k] + s1 * w1[1536 + k] + b1[k];
        hv = fmaxf(hv, 0.f);
        #pragma unroll
        for (int h = 0; h < 6; ++h) acc[h] += hv * w2[k * 6 + h];
    }
    #pragma unroll
    for (int h = 0; h < 6; ++h) btab[t * 6 + h] = acc[h];
}

__global__ __launch_bounds__(256) void ln_stats(const float* __restrict__ x, float* __restrict__ st) {
    int r = blockIdx.x * 4 + (threadIdx.x >> 6);
    int lane = threadIdx.x & 63;
    const float* p = x + (size_t)r * 192;
    float a0 = p[lane], a1 = p[lane + 64], a2 = p[lane + 128];
    float s = a0 + a1 + a2;
    float q = a0 * a0 + a1 * a1 + a2 * a2;
    #pragma unroll
    for (int off = 1; off < 64; off <<= 1) {
        s += __shfl_xor(s, off);
        q += __shfl_xor(q, off);
    }
    if (lane == 0) {
        float m = s * (1.f / 192.f);
        float v = q * (1.f / 192.f) - m * m;
        st[2 * r] = m;
        st[2 * r + 1] = rsqrtf(v + 1e-5f);
    }
}

// LN (stats + apply) in one pass; writes bf16 rows in WINDOWED order.
__global__ __launch_bounds__(256) void ln_full(
    const float* __restrict__ xin, const float* __restrict__ g, const float* __restrict__ b,
    unsigned short* __restrict__ ow) {
    int r = blockIdx.x * 4 + (threadIdx.x >> 6);
    int lane = threadIdx.x & 63;
    const float* p = xin + (size_t)r * 192;
    float a0 = p[lane], a1 = p[lane + 64], a2 = p[lane + 128];
    float s = a0 + a1 + a2;
    float q = a0 * a0 + a1 * a1 + a2 * a2;
    #pragma unroll
    for (int off = 1; off < 64; off <<= 1) {
        s += __shfl_xor(s, off);
        q += __shfl_xor(q, off);
    }
    float mean = s * (1.f / 192.f);
    float rstd = rsqrtf(q * (1.f / 192.f) - mean * mean + 1e-5f);
    unsigned short* o = ow + (size_t)wperm_inv(r) * 192;
    o[lane]       = f2b((a0 - mean) * rstd * g[lane] + b[lane]);
    o[lane + 64]  = f2b((a1 - mean) * rstd * g[lane + 64] + b[lane + 64]);
    o[lane + 128] = f2b((a2 - mean) * rstd * g[lane + 128] + b[lane + 128]);
}

// ---------------- shared GEMM (K=192), tile 128x192, 4 waves ----------------
// MODE 0: A = xnw bf16 (windowed LN1(x)) -> q/k/v scatter (q scaled)
// MODE 1: A = attn_out bf16 (windowed) -> d_out[perm] = x[perm] + A@W + b
// MODE 2: A = LN2(d_out) computed from fp32+stats -> m1 = gelu(A@W+b) bf16
// MODE 3: A = on2w bf16 (windowed LN2) -> m1[wperm] = gelu(A@W+b) bf16
template<int MODE>
__global__ __launch_bounds__(256) void gemm192(
    const float* __restrict__ Af, const unsigned short* __restrict__ Ab,
    const float* __restrict__ stats, const float* __restrict__ lng, const float* __restrict__ lnb,
    const unsigned short* __restrict__ Bt, const float* __restrict__ bias,
    unsigned short* __restrict__ oq, unsigned short* __restrict__ ok2, unsigned short* __restrict__ ov,
    const float* __restrict__ resid, float* __restrict__ ofp, unsigned short* __restrict__ obf) {
    __shared__ __align__(16) unsigned short As[128 * 72];
    __shared__ __align__(16) unsigned short Bs[192 * 72];
    const int t = threadIdx.x;
    const int lane = t & 63;
    const int wv = t >> 6, wm = wv >> 1, wn = wv & 1;
    const int n0 = blockIdx.x * 192;
    const int m0 = blockIdx.y * 128;
    const int l15 = lane & 15, lq = lane >> 4;

    f32x4 acc[4][6];
    #pragma unroll
    for (int i = 0; i < 4; ++i)
        #pragma unroll
        for (int j = 0; j < 6; ++j) acc[i][j] = (f32x4){0.f, 0.f, 0.f, 0.f};

    for (int k0 = 0; k0 < 192; k0 += 64) {
        if constexpr (MODE == 2) {
            #pragma unroll
            for (int i = 0; i < 8; ++i) {
                int c = t + i * 256;
                int row = c >> 4, ch = c & 15;
                int m = m0 + row;
                f32x4 v = *(const f32x4*)(Af + (size_t)m * 192 + k0 + ch * 4);
                float mean = stats[2 * m], rstd = stats[2 * m + 1];
                u16x4 pk;
                #pragma unroll
                for (int j = 0; j < 4; ++j) {
                    int kk = k0 + ch * 4 + j;
                    pk[j] = f2b((v[j] - mean) * rstd * lng[kk] + lnb[kk]);
                }
                *(u16x4*)&As[row * 72 + ch * 4] = pk;
            }
        } else {
            #pragma unroll
            for (int i = 0; i < 4; ++i) {
                int c = t + i * 256;
                int row = c >> 3, ch = c & 7;
                *(u16x8*)&As[row * 72 + ch * 8] =
                    *(const u16x8*)(Ab + (size_t)(m0 + row) * 192 + k0 + ch * 8);
            }
        }
        #pragma unroll
        for (int i = 0; i < 6; ++i) {
            int c = t + i * 256;
            int row = c >> 3, ch = c & 7;
            *(u16x8*)&Bs[row * 72 + ch * 8] =
                *(const u16x8*)(Bt + (size_t)(n0 + row) * 192 + k0 + ch * 8);
        }
        __syncthreads();
        #pragma unroll
        for (int kk = 0; kk < 2; ++kk) {
            bf16x8 a[4], bb[6];
            #pragma unroll
            for (int mt = 0; mt < 4; ++mt)
                a[mt] = *(bf16x8*)&As[(wm * 64 + mt * 16 + l15) * 72 + kk * 32 + lq * 8];
            #pragma unroll
            for (int nt = 0; nt < 6; ++nt)
                bb[nt] = *(bf16x8*)&Bs[(wn * 96 + nt * 16 + l15) * 72 + kk * 32 + lq * 8];
            #pragma unroll
            for (int mt = 0; mt < 4; ++mt)
                #pragma unroll
                for (int nt = 0; nt < 6; ++nt)
                    acc[mt][nt] = __builtin_amdgcn_mfma_f32_16x16x32_bf16(a[mt], bb[nt], acc[mt][nt], 0, 0, 0);
        }
        __syncthreads();
    }
    #pragma unroll
    for (int mt = 0; mt < 4; ++mt) {
        #pragma unroll
        for (int nt = 0; nt < 6; ++nt) {
            #pragma unroll
            for (int r = 0; r < 4; ++r) {
                int m = m0 + wm * 64 + mt * 16 + lq * 4 + r;
                int c = n0 + wn * 96 + nt * 16 + l15;
                float v = acc[mt][nt][r] + bias[c];
                if constexpr (MODE == 0) {
                    int which = c / 192;
                    int head = (c % 192) >> 5;
                    int d = c & 31;
                    int w = m >> 6, n = m & 63;
                    unsigned short* dst = (which == 0) ? oq : (which == 1) ? ok2 : ov;
                    if (which == 0) v *= 0.17677669529663689f;  // HD^-0.5
                    dst[((size_t)(w * 6 + head) * 64 + n) * 32 + d] = f2b(v);
                } else if constexpr (MODE == 1) {
                    int r2 = wperm(m);
                    size_t idx = (size_t)r2 * 192 + c;
                    ofp[idx] = resid[idx] + v;
                } else if constexpr (MODE == 2) {
                    obf[(size_t)m * 768 + c] = f2b(gelu_fast(v));
                } else {
                    obf[(size_t)wperm(m) * 768 + c] = f2b(gelu_fast(v));
                }
            }
        }
    }
}

// ---------------- attention: one wave per (window, head) ----------------
__global__ __launch_bounds__(64) void attn_win(
    const unsigned short* __restrict__ qb, const unsigned short* __restrict__ kb,
    const unsigned short* __restrict__ vb, const float* __restrict__ btab,
    unsigned short* __restrict__ ao) {
    __shared__ float sb[1350];
    __shared__ __align__(16) unsigned short pl[64 * 72];
    __shared__ __align__(16) unsigned short vT[32 * 72];
    const int bid = blockIdx.x;            // = w*6 + h
    const int w = bid / 6, h = bid - w * 6;
    const int lane = threadIdx.x;
    const int l15 = lane & 15, lq = lane >> 4;

    for (int i = lane; i < 1350; i += 64) sb[i] = btab[i];

    const unsigned short* qp = qb + (size_t)bid * 2048;
    const unsigned short* kp = kb + (size_t)bid * 2048;
    const unsigned short* vp = vb + (size_t)bid * 2048;

    bf16x8 qf[4], kf[4];
    #pragma unroll
    for (int i = 0; i < 4; ++i) {
        qf[i] = *(const bf16x8*)(qp + (i * 16 + l15) * 32 + lq * 8);
        kf[i] = *(const bf16x8*)(kp + (i * 16 + l15) * 32 + lq * 8);
    }
    #pragma unroll
    for (int i = 0; i < 4; ++i) {  // V transposed into LDS
        int c = lane + i * 64;
        int mr = c >> 2, d0 = (c & 3) * 8;
        u16x8 v = *(const u16x8*)(vp + mr * 32 + d0);
        #pragma unroll
        for (int j = 0; j < 8; ++j) vT[(d0 + j) * 72 + mr] = v[j];
    }
    f32x4 s[4][4];
    #pragma unroll
    for (int mt = 0; mt < 4; ++mt)
        #pragma unroll
        for (int nt = 0; nt < 4; ++nt)
            s[mt][nt] = __builtin_amdgcn_mfma_f32_16x16x32_bf16(
                qf[mt], kf[nt], (f32x4){0.f, 0.f, 0.f, 0.f}, 0, 0, 0);
    __syncthreads();
    // bias + softmax (rows over 16 lanes x 4 col-tiles)
    #pragma unroll
    for (int mt = 0; mt < 4; ++mt) {
        #pragma unroll
        for (int r = 0; r < 4; ++r) {
            int n = mt * 16 + lq * 4 + r;
            int ny = n >> 3, nx = n & 7;
            float sv[4];
            float mx = -1e30f;
            #pragma unroll
            for (int nt = 0; nt < 4; ++nt) {
                int m = nt * 16 + l15;
                int idx = (ny - (m >> 3) + 7) * 15 + (nx - (m & 7) + 7);
                float val = s[mt][nt][r] + sb[idx * 6 + h];
                sv[nt] = val;
                mx = fmaxf(mx, val);
            }
            #pragma unroll
            for (int off = 1; off < 16; off <<= 1) mx = fmaxf(mx, __shfl_xor(mx, off));
            float sum = 0.f;
            #pragma unroll
            for (int nt = 0; nt < 4; ++nt) { sv[nt] = __expf(sv[nt] - mx); sum += sv[nt]; }
            #pragma unroll
            for (int off = 1; off < 16; off <<= 1) sum += __shfl_xor(sum, off);
            float inv = 1.f / sum;
            #pragma unroll
            for (int nt = 0; nt < 4; ++nt)
                pl[n * 72 + nt * 16 + l15] = f2b(sv[nt] * inv);
        }
    }
    __syncthreads();
    f32x4 o[4][2];
    #pragma unroll
    for (int i = 0; i < 4; ++i)
        #pragma unroll
        for (int j = 0; j < 2; ++j) o[i][j] = (f32x4){0.f, 0.f, 0.f, 0.f};
    #pragma unroll
    for (int mt = 0; mt < 4; ++mt)
        #pragma unroll
        for (int kk = 0; kk < 2; ++kk) {
            bf16x8 a = *(bf16x8*)&pl[(mt * 16 + l15) * 72 + kk * 32 + lq * 8];
            #pragma unroll
            for (int dt = 0; dt < 2; ++dt) {
                bf16x8 b = *(bf16x8*)&vT[(dt * 16 + l15) * 72 + kk * 32 + lq * 8];
                o[mt][dt] = __builtin_amdgcn_mfma_f32_16x16x32_bf16(a, b, o[mt][dt], 0, 0, 0);
            }
        }
    #pragma unroll
    for (int mt = 0; mt < 4; ++mt)
        #pragma unroll
        for (int dt = 0; dt < 2; ++dt)
            #pragma unroll
            for (int r = 0; r < 4; ++r) {
                int n = mt * 16 + lq * 4 + r;
                int d = dt * 16 + l15;
                ao[((size_t)w * 64 + n) * 192 + h * 32 + d] = f2b(o[mt][dt][r]);
            }
}

// -------- fused depthwise 3x3 conv + gelu + fc2 + residual ------------------
// v8: register-lean conv. 256 threads, tile 32x * 2y. The two output rows are
// computed SEQUENTIALLY (no shared row buffer): live set ~a[8]+transients
// ~50-60 arch regs + 48 AGPR -> total <=128 -> 4 waves/SIMD naturally.
// NO min-waves launch-bounds arg (that mechanism caused the v4/v6/v7 spills:
// occupancy reg steps are 64/128/256 total; a "3-waves" request caps at 128).
// Duplicated y-overlap loads hit L1 (block chunk working set ~2KB).
__global__ __launch_bounds__(256) void conv_fc2_v8(
    const unsigned short* __restrict__ m1, const unsigned short* __restrict__ dwwT,
    const float* __restrict__ dwb, const unsigned short* __restrict__ fc2T,
    const float* __restrict__ fc2b, float* __restrict__ out) {
    __shared__ __align__(16) unsigned short As[64 * 72];
    __shared__ __align__(16) unsigned short Bs[192 * 72];
    const int t = threadIdx.x;
    // XCD band swizzle: each XCD gets a contiguous 64-row band
    const int g = ((blockIdx.x & 7) << 8) + (blockIdx.x >> 3);
    const int b = g >> 10, ypair = (g >> 3) & 127, xq = g & 7;
    const int y0 = ypair * 2, x0 = xq * 32;
    const int cg = t & 7, lx = t >> 3;               // lx in [0,32)
    const size_t ibase = (size_t)b * 65536;

    const int lane = t & 63, wv = t >> 6, wm = wv >> 1, wn = wv & 1;
    const int l15 = lane & 15, lq = lane >> 4;

    f32x4 acc[2][6];
    #pragma unroll
    for (int i = 0; i < 2; ++i)
        #pragma unroll
        for (int j = 0; j < 6; ++j) acc[i][j] = (f32x4){0.f, 0.f, 0.f, 0.f};

    for (int k0 = 0; k0 < 768; k0 += 64) {
        const int c0 = k0 + cg * 8;
        const int xx0 = x0 + lx;
        f32x4 bs0 = *(const f32x4*)(dwb + c0);
        f32x4 bs1 = *(const f32x4*)(dwb + c0 + 4);
        // ---- conv: two output rows sequentially, 8 ch per thread ----
        #pragma unroll
        for (int orow = 0; orow < 2; ++orow) {
            const int oy = y0 + orow;
            float a[8];
            #pragma unroll
            for (int j = 0; j < 4; ++j) { a[j] = bs0[j]; a[4 + j] = bs1[j]; }
            #pragma unroll
            for (int ky = 0; ky < 3; ++ky) {
                int yy = oy + ky - 1;
                if ((unsigned)yy >= 256u) continue;
                #pragma unroll
                for (int kx = 0; kx < 3; ++kx) {
                    int xx = xx0 + kx - 1;
                    if ((unsigned)xx >= 256u) continue;
                    u16x8 w8 = *(const u16x8*)(dwwT + (ky * 3 + kx) * 768 + c0);
                    u16x8 in = *(const u16x8*)(m1 + ((ibase + (size_t)yy * 256 + xx) * 768 + c0));
                    #pragma unroll
                    for (int j = 0; j < 8; ++j) a[j] += b2f(in[j]) * b2f(w8[j]);
                }
            }
            u16x8 o;
            #pragma unroll
            for (int j = 0; j < 8; ++j) o[j] = f2b(gelu_fast(a[j]));
            *(u16x8*)&As[(orow * 32 + lx) * 72 + cg * 8] = o;
        }
        // ---- B staging: fc2T[192][k0..k0+64) ----
        #pragma unroll
        for (int i = 0; i < 6; ++i) {
            int c = t + i * 256;
            int nr = c >> 3, ch = c & 7;
            *(u16x8*)&Bs[nr * 72 + ch * 8] =
                *(const u16x8*)(fc2T + (size_t)nr * 768 + k0 + ch * 8);
        }
        __syncthreads();
        #pragma unroll
        for (int kk = 0; kk < 2; ++kk) {
            bf16x8 af[2], bb[6];
            #pragma unroll
            for (int mt = 0; mt < 2; ++mt)
                af[mt] = *(bf16x8*)&As[(wm * 32 + mt * 16 + l15) * 72 + kk * 32 + lq * 8];
            #pragma unroll
            for (int nt = 0; nt < 6; ++nt)
                bb[nt] = *(bf16x8*)&Bs[(wn * 96 + nt * 16 + l15) * 72 + kk * 32 + lq * 8];
            #pragma unroll
            for (int mt = 0; mt < 2; ++mt)
                #pragma unroll
                for (int nt = 0; nt < 6; ++nt)
                    acc[mt][nt] = __builtin_amdgcn_mfma_f32_16x16x32_bf16(af[mt], bb[nt], acc[mt][nt], 0, 0, 0);
        }
        __syncthreads();
    }
    #pragma unroll
    for (int mt = 0; mt < 2; ++mt)
        #pragma unroll
        for (int nt = 0; nt < 6; ++nt)
            #pragma unroll
            for (int r = 0; r < 4; ++r) {
                int ml = wm * 32 + mt * 16 + lq * 4 + r;
                int iy = ml >> 5, lxx = ml & 31;
                int col = wn * 96 + nt * 16 + l15;
                size_t idx = (ibase + (size_t)(y0 + iy) * 256 + x0 + lxx) * 192 + col;
                out[idx] = out[idx] + acc[mt][nt][r] + fc2b[col];
            }
}

// ---------------- host ----------------
extern "C" void kernel_launch(void* const* d_in, const int* in_sizes, int n_in,
                              void* d_out, int out_size, void* d_ws, size_t ws_size,
                              hipStream_t stream) {
    (void)in_sizes; (void)n_in; (void)out_size;
    const float* x     = (const float*)d_in[0];
    const float* scale = (const float*)d_in[1];
    const float* n1g   = (const float*)d_in[2];
    const float* n1b   = (const float*)d_in[3];
    const float* qkvw  = (const float*)d_in[4];
    const float* qkvb  = (const float*)d_in[5];
    const float* projw = (const float*)d_in[6];
    const float* projb = (const float*)d_in[7];
    const float* cw1   = (const float*)d_in[8];
    const float* cb1   = (const float*)d_in[9];
    const float* cw2   = (const float*)d_in[10];
    const float* cb2   = (const float*)d_in[11];
    const float* n2g   = (const float*)d_in[12];
    const float* n2b   = (const float*)d_in[13];
    const float* fc1w  = (const float*)d_in[14];
    const float* fc1b  = (const float*)d_in[15];
    const float* fc2w  = (const float*)d_in[16];
    const float* fc2b  = (const float*)d_in[17];
    const float* dww   = (const float*)d_in[18];
    const float* dwb   = (const float*)d_in[19];
    float* out = (float*)d_out;

    char* ws = (char*)d_ws;
    unsigned short* qkvT  = (unsigned short*)ws;       // [576][192]
    unsigned short* projT = qkvT + 110592;             // [192][192]
    unsigned short* fc1T  = projT + 36864;             // [768][192]
    unsigned short* fc2T  = fc1T + 147456;             // [192][768]
    unsigned short* dwwT  = fc2T + 147456;             // [9][768] tap-major bf16
    float* btab  = (float*)(ws + 1048576);             // [225][6]
    float* stats = (float*)(ws + 2097152);             // [131072][2]
    unsigned short* pool = (unsigned short*)(ws + 4194304);
    const size_t S = 25165824;                          // 50.3MB slots (ushort count)
    unsigned short* qb = pool;
    unsigned short* kb = pool + S;
    unsigned short* vb = pool + 2 * S;
    unsigned short* ab = pool + 3 * S;
    unsigned short* m1 = pool;                          // [2*65536][768] bf16 (201.3MB)
    unsigned short* on2w = pool + 4 * S;                // optional 5th slot
    unsigned short* xnw = (unsigned short*)d_out;       // LN1 bf16 (windowed), d_out as scratch
    const bool five_slots = ws_size >= (size_t)4194304 + (size_t)5 * S * 2;

    transpose_w<<<432, 256, 0, stream>>>(qkvw, qkvT, 192, 576);
    transpose_w<<<144, 256, 0, stream>>>(projw, projT, 192, 192);
    transpose_w<<<576, 256, 0, stream>>>(fc1w, fc1T, 192, 768);
    transpose_w<<<576, 256, 0, stream>>>(fc2w, fc2T, 768, 192);
    transpose_w<<<27, 256, 0, stream>>>(dww, dwwT, 768, 9);   // dwwT[tap*768+c]=dww[c*9+tap]
    cpb_kernel<<<1, 256, 0, stream>>>(scale, cw1, cb1, cw2, cb2, btab);

    ln_full<<<32768, 256, 0, stream>>>(x, n1g, n1b, xnw);
    gemm192<0><<<dim3(3, 1024), 256, 0, stream>>>(
        (const float*)nullptr, xnw, (const float*)nullptr, (const float*)nullptr,
        (const float*)nullptr, qkvT, qkvb,
        qb, kb, vb, (const float*)nullptr, (float*)nullptr, (unsigned short*)nullptr);
    attn_win<<<12288, 64, 0, stream>>>(qb, kb, vb, btab, ab);
    gemm192<1><<<dim3(1, 1024), 256, 0, stream>>>(
        (const float*)nullptr, ab, (const float*)nullptr, (const float*)nullptr,
        (const float*)nullptr, projT, projb,
        (unsigned short*)nullptr, (unsigned short*)nullptr, (unsigned short*)nullptr,
        x, out, (unsigned short*)nullptr);
    if (five_slots) {
        ln_full<<<32768, 256, 0, stream>>>(out, n2g, n2b, on2w);
        gemm192<3><<<dim3(4, 1024), 256, 0, stream>>>(
            (const float*)nullptr, on2w, (const float*)nullptr, (const float*)nullptr,
            (const float*)nullptr, fc1T, fc1b,
            (unsigned short*)nullptr, (unsigned short*)nullptr, (unsigned short*)nullptr,
            (const float*)nullptr, (float*)nullptr, m1);
    } else {
        ln_stats<<<32768, 256, 0, stream>>>(out, stats);
        gemm192<2><<<dim3(4, 1024), 256, 0, stream>>>(
            out, (const unsigned short*)nullptr, stats, n2g, n2b, fc1T, fc1b,
            (unsigned short*)nullptr, (unsigned short*)nullptr, (unsigned short*)nullptr,
            (const float*)nullptr, (float*)nullptr, m1);
    }
    conv_fc2_v8<<<2048, 256, 0, stream>>>(m1, dwwT, dwb, fc2T, fc2b, out);
}